// Round 1
// baseline (28134.042 us; speedup 1.0000x reference)
//
#include <hip/hip_runtime.h>
#include <math.h>

// Problem constants (from reference setup_inputs)
#define T_TOK 8192      // B*S = 4*2048 tokens
#define H_DIM 1024
#define F_DIM 2048
#define EI    32        // individual (sparse) experts
#define ES    4         // shared (dense) experts
#define NE    36        // EI + ES
#define TOPK  16
#define TT    8         // tokens per expert-kernel block

#define NEGF  (-3.0e38f)

// ---------------- workspace layout (bytes) ----------------
// [0,256)                       : int counts[64]   (only 0..35 used)
// [256, 256+NE*T*4)             : int eidx[NE][T]  gathered token ids
// [.., +NE*T*4)                 : float ew[NE][T]  gathered combine weights
// [.., +T*EI*4)                 : float probs[T][EI] full softmax (for aux)
#define OFF_EIDX   256
#define OFF_EW     (OFF_EIDX + NE*T_TOK*4)
#define OFF_PROBS  (OFF_EW   + NE*T_TOK*4)
#define WS_BYTES   (OFF_PROBS + T_TOK*EI*4)

// =====================================================================
// Gate: logits, softmax, top-16, gather lists, shared-expert weights
// one wave (64 lanes) per token; 4 waves / block
// =====================================================================
__global__ __launch_bounds__(256) void gate_kernel(
    const float* __restrict__ x,
    const float* __restrict__ gi,   // [H][EI]
    const float* __restrict__ gs,   // [H][ES]
    int*   __restrict__ counts,
    int*   __restrict__ eidx,
    float* __restrict__ ew,
    float* __restrict__ probs)
{
    const int wave = threadIdx.x >> 6;
    const int lane = threadIdx.x & 63;
    const int t = blockIdx.x * 4 + wave;   // grid is exact: 2048*4 = 8192

    const float* xr = x + (long)t * H_DIM;
    float xv[16];
#pragma unroll
    for (int k = 0; k < 16; ++k) xv[k] = xr[lane + 64 * k];

    // ---- individual-expert logits: lane e (<32) ends holding logit[e] ----
    float myl = NEGF;
    for (int e = 0; e < EI; ++e) {
        float s = 0.f;
#pragma unroll
        for (int k = 0; k < 16; ++k) s += xv[k] * gi[(lane + 64 * k) * EI + e];
        for (int off = 32; off; off >>= 1) s += __shfl_xor(s, off);
        if (lane == e) myl = s;
    }

    // ---- top-16 selection (wave-parallel argmax extraction) ----
    float v = (lane < EI) ? myl : NEGF;
    float m0 = 0.f, sumexp = 0.f;
    float selv = NEGF; int seli = 0;
    for (int j = 0; j < TOPK; ++j) {
        float bv = v; int bi = lane;
        for (int off = 32; off; off >>= 1) {
            float ov = __shfl_xor(bv, off);
            int   oi = __shfl_xor(bi, off);
            if (ov > bv || (ov == bv && oi < bi)) { bv = ov; bi = oi; }
        }
        if (j == 0) m0 = bv;               // global max (top-1)
        sumexp += expf(bv - m0);           // identical on all lanes
        if (lane == j) { selv = bv; seli = bi; }
        if (lane == bi) v = NEGF;          // remove winner
    }
    if (lane < TOPK) {
        float w = expf(selv - m0) / sumexp;          // renormalized top-k softmax
        int slot = atomicAdd(&counts[seli], 1);
        eidx[seli * T_TOK + slot] = t;
        ew  [seli * T_TOK + slot] = w;
    }

    // ---- full softmax probs (for aux loss) ----
    {
        float p  = (lane < EI) ? expf(myl - m0) : 0.f;
        float ps = p;
        for (int off = 32; off; off >>= 1) ps += __shfl_xor(ps, off);
        if (lane < EI) probs[(long)t * EI + lane] = p / ps;
    }

    // ---- shared (dense) experts: softmax over 4 logits ----
    float mysl = NEGF;
    for (int e = 0; e < ES; ++e) {
        float s = 0.f;
#pragma unroll
        for (int k = 0; k < 16; ++k) s += xv[k] * gs[(lane + 64 * k) * ES + e];
        for (int off = 32; off; off >>= 1) s += __shfl_xor(s, off);
        if (lane == e) mysl = s;
    }
    {
        float a = (lane < ES) ? mysl : NEGF;
        float mx = a;
        for (int off = 1; off < 4; off <<= 1) mx = fmaxf(mx, __shfl_xor(mx, off));
        float exv = (lane < ES) ? expf(a - mx) : 0.f;
        float se = exv;
        for (int off = 1; off < 4; off <<= 1) se += __shfl_xor(se, off);
        if (lane < ES) {
            int e = EI + lane;                 // identity list: slot = t
            eidx[(long)e * T_TOK + t] = t;
            ew  [(long)e * T_TOK + t] = exv / se;
        }
    }
}

// =====================================================================
// Fused expert MLP: per block = 1 expert x 8 gathered tokens.
// Phase B: h = relu(x@W1+b1) by F-halves into LDS; Phase C: out += h@W2
// accumulated in registers; epilogue: y += w*(out+b2) via atomicAdd.
// Weights read exactly once per block (4 FLOP/byte, L2/LLC-resident).
// =====================================================================
__global__ __launch_bounds__(256) void expert_kernel(
    const float* __restrict__ x,
    const float* __restrict__ W1i, const float* __restrict__ b1i,
    const float* __restrict__ W2i, const float* __restrict__ b2i,
    const float* __restrict__ W1s, const float* __restrict__ b1s,
    const float* __restrict__ W2s, const float* __restrict__ b2s,
    const int*   __restrict__ counts,
    const int*   __restrict__ eidx, const float* __restrict__ ew,
    float* __restrict__ y)
{
    const int e  = blockIdx.x >> 10;          // 1024 = 8192/TT tile-blocks/expert
    const int bt = blockIdx.x & 1023;
    const int n  = (e < EI) ? counts[e] : T_TOK;
    const int base = bt * TT;
    if (base >= n) return;
    const int tid = threadIdx.x;

    __shared__ float4 xs4[TT][H_DIM / 4];     // 32 KB
    __shared__ float4 hs4[TT][H_DIM / 4];     // 32 KB (one F-half at a time)
    __shared__ int   tok[TT];
    __shared__ float twt[TT];

    if (tid < TT) {
        int r = base + tid;
        if (r < n) { tok[tid] = eidx[(long)e * T_TOK + r]; twt[tid] = ew[(long)e * T_TOK + r]; }
        else       { tok[tid] = 0;                          twt[tid] = 0.f; }
    }
    __syncthreads();

#pragma unroll
    for (int i = 0; i < TT; ++i) {            // 256 float4 per row, 1/thread
        const float4* src = (const float4*)(x + (long)tok[i] * H_DIM);
        xs4[i][tid] = src[tid];
    }
    __syncthreads();

    const float *W1p, *b1p, *W2p, *b2p;
    if (e < EI) {
        W1p = W1i + (long)e * H_DIM * F_DIM;  b1p = b1i + (long)e * F_DIM;
        W2p = W2i + (long)e * F_DIM * H_DIM;  b2p = b2i + (long)e * H_DIM;
    } else {
        int s = e - EI;
        W1p = W1s + (long)s * H_DIM * F_DIM;  b1p = b1s + (long)s * F_DIM;
        W2p = W2s + (long)s * F_DIM * H_DIM;  b2p = b2s + (long)s * H_DIM;
    }

    float oa[TT][4];
#pragma unroll
    for (int t = 0; t < TT; ++t) { oa[t][0]=0.f; oa[t][1]=0.f; oa[t][2]=0.f; oa[t][3]=0.f; }

    const int c0 = tid * 4;                   // this thread's 4 columns within a 1024-pass

    for (int half = 0; half < 2; ++half) {
        const int fbase = half * (F_DIM / 2);

        // ---- Phase B: ba[t][j] = sum_hh x[t][hh] * W1[hh][fbase+c0+j] ----
        float ba[TT][4];
#pragma unroll
        for (int t = 0; t < TT; ++t) { ba[t][0]=0.f; ba[t][1]=0.f; ba[t][2]=0.f; ba[t][3]=0.f; }

        const float* w1c = W1p + fbase + c0;
        for (int hh4 = 0; hh4 < H_DIM / 4; ++hh4) {
            float4 xv[TT];
#pragma unroll
            for (int t = 0; t < TT; ++t) xv[t] = xs4[t][hh4];
#pragma unroll
            for (int u = 0; u < 4; ++u) {
                float4 w = *(const float4*)(w1c + (long)(hh4 * 4 + u) * F_DIM);
#pragma unroll
                for (int t = 0; t < TT; ++t) {
                    float xu = (u == 0) ? xv[t].x : (u == 1) ? xv[t].y : (u == 2) ? xv[t].z : xv[t].w;
                    ba[t][0] += xu * w.x; ba[t][1] += xu * w.y;
                    ba[t][2] += xu * w.z; ba[t][3] += xu * w.w;
                }
            }
        }

        // bias + relu -> hs
        float4 bb = *(const float4*)(b1p + fbase + c0);
        __syncthreads();                       // prev-half Phase C done reading hs
#pragma unroll
        for (int t = 0; t < TT; ++t) {
            float4 hv;
            hv.x = fmaxf(ba[t][0] + bb.x, 0.f);
            hv.y = fmaxf(ba[t][1] + bb.y, 0.f);
            hv.z = fmaxf(ba[t][2] + bb.z, 0.f);
            hv.w = fmaxf(ba[t][3] + bb.w, 0.f);
            hs4[t][tid] = hv;
        }
        __syncthreads();

        // ---- Phase C: oa[t][j] += sum_ff h[t][ff] * W2[fbase+ff][c0+j] ----
        const float* w2c = W2p + (long)fbase * H_DIM + c0;
        for (int ff4 = 0; ff4 < H_DIM / 4; ++ff4) {
            float4 hv[TT];
#pragma unroll
            for (int t = 0; t < TT; ++t) hv[t] = hs4[t][ff4];
#pragma unroll
            for (int u = 0; u < 4; ++u) {
                float4 w = *(const float4*)(w2c + (long)(ff4 * 4 + u) * H_DIM);
#pragma unroll
                for (int t = 0; t < TT; ++t) {
                    float hu = (u == 0) ? hv[t].x : (u == 1) ? hv[t].y : (u == 2) ? hv[t].z : hv[t].w;
                    oa[t][0] += hu * w.x; oa[t][1] += hu * w.y;
                    oa[t][2] += hu * w.z; oa[t][3] += hu * w.w;
                }
            }
        }
        __syncthreads();
    }

    // ---- epilogue: y[tok] += w * (out + b2) ----
    float4 b2v = *(const float4*)(b2p + c0);
#pragma unroll
    for (int t = 0; t < TT; ++t) {
        float wt = twt[t];
        if (wt != 0.f) {
            float* dst = y + (long)tok[t] * H_DIM + c0;
            atomicAdd(dst + 0, wt * (oa[t][0] + b2v.x));
            atomicAdd(dst + 1, wt * (oa[t][1] + b2v.y));
            atomicAdd(dst + 2, wt * (oa[t][2] + b2v.z));
            atomicAdd(dst + 3, wt * (oa[t][3] + b2v.w));
        }
    }
}

// =====================================================================
// Aux loss: aux = EI * sum_e (counts[e]/T) * mean_t probs[t][e]
// =====================================================================
__global__ __launch_bounds__(256) void aux_kernel(
    const float* __restrict__ probs, const int* __restrict__ counts,
    float* __restrict__ out)
{
    __shared__ float sacc[256];
    const int per_blk = (T_TOK * EI) / 256;        // 1024 elements per block
    long start = (long)blockIdx.x * per_blk;
    float p = 0.f;
    for (int i = threadIdx.x; i < per_blk; i += 256) {
        long idx = start + i;
        p += (float)counts[idx & (EI - 1)] * probs[idx];
    }
    sacc[threadIdx.x] = p;
    __syncthreads();
    for (int s = 128; s; s >>= 1) {
        if (threadIdx.x < s) sacc[threadIdx.x] += sacc[threadIdx.x + s];
        __syncthreads();
    }
    if (threadIdx.x == 0) {
        float scale = (float)EI / ((float)T_TOK * (float)T_TOK);
        atomicAdd(out + (long)T_TOK * H_DIM, scale * sacc[0]);
    }
}

// =====================================================================
extern "C" void kernel_launch(void* const* d_in, const int* in_sizes, int n_in,
                              void* d_out, int out_size, void* d_ws, size_t ws_size,
                              hipStream_t stream)
{
    const float* x    = (const float*)d_in[0];
    const float* gi   = (const float*)d_in[1];
    const float* W1i  = (const float*)d_in[2];
    const float* b1i  = (const float*)d_in[3];
    const float* W2i  = (const float*)d_in[4];
    const float* b2i  = (const float*)d_in[5];
    const float* gs   = (const float*)d_in[6];
    const float* W1s  = (const float*)d_in[7];
    const float* b1s  = (const float*)d_in[8];
    const float* W2s  = (const float*)d_in[9];
    const float* b2s  = (const float*)d_in[10];
    float* y = (float*)d_out;

    char* ws = (char*)d_ws;
    int*   counts = (int*)  (ws);
    int*   eidx   = (int*)  (ws + OFF_EIDX);
    float* ew     = (float*)(ws + OFF_EW);
    float* probs  = (float*)(ws + OFF_PROBS);

    // zero y (+aux slot) and gather counters; d_out/d_ws are poisoned each run
    hipMemsetAsync(d_out, 0, (size_t)out_size * sizeof(float), stream);
    hipMemsetAsync(counts, 0, 256, stream);

    gate_kernel<<<T_TOK / 4, 256, 0, stream>>>(x, gi, gs, counts, eidx, ew, probs);

    expert_kernel<<<NE * (T_TOK / TT), 256, 0, stream>>>(
        x, W1i, b1i, W2i, b2i, W1s, b1s, W2s, b2s, counts, eidx, ew, y);

    aux_kernel<<<256, 256, 0, stream>>>(probs, counts, y);
}

// Round 4
// 11898.709 us; speedup vs baseline: 2.3645x; 2.3645x over previous
//
#include <hip/hip_runtime.h>
#include <math.h>

// Problem constants (from reference setup_inputs)
#define T_TOK 8192      // B*S = 4*2048 tokens
#define H_DIM 1024
#define F_DIM 2048
#define EI    32        // individual (sparse) experts
#define ES    4         // shared (dense) experts
#define NE    36        // EI + ES
#define TOPK  16

#define NEGF  (-3.0e38f)

typedef _Float16 f16;
typedef _Float16 f16x8 __attribute__((ext_vector_type(8)));
typedef float    f32x4 __attribute__((ext_vector_type(4)));

// ---------------- workspace layout (bytes) ----------------
// shared front section (both paths):
#define OFF_EIDX   256
#define OFF_EW     (OFF_EIDX + NE*T_TOK*4)
#define OFF_PROBS  (OFF_EW   + NE*T_TOK*4)
// fp16 path extras:
#define OFF_XH     (OFF_PROBS + T_TOK*EI*4)
#define OFF_W1TI   (OFF_XH   + T_TOK*H_DIM*2)
#define OFF_W2TI   (OFF_W1TI + (size_t)EI*H_DIM*F_DIM*2)
#define OFF_W1TS   (OFF_W2TI + (size_t)EI*H_DIM*F_DIM*2)
#define OFF_W2TS   (OFF_W1TS + (size_t)ES*H_DIM*F_DIM*2)
#define WS_FP16_NEED (OFF_W2TS + (size_t)ES*H_DIM*F_DIM*2)

// fp16 expert kernel tile config
#define M_TILE 64
#define FC     128
#define NCHUNK (F_DIM/FC)       // 16
#define MT_PER_E (T_TOK/M_TILE) // 128

// =====================================================================
// Gate: logits, softmax, top-16, gather lists, shared-expert weights
// one wave (64 lanes) per token; 4 waves / block
// =====================================================================
__global__ __launch_bounds__(256) void gate_kernel(
    const float* __restrict__ x,
    const float* __restrict__ gi,   // [H][EI]
    const float* __restrict__ gs,   // [H][ES]
    int*   __restrict__ counts,
    int*   __restrict__ eidx,
    float* __restrict__ ew,
    float* __restrict__ probs)
{
    const int wave = threadIdx.x >> 6;
    const int lane = threadIdx.x & 63;
    const int t = blockIdx.x * 4 + wave;

    const float* xr = x + (long)t * H_DIM;
    float xv[16];
#pragma unroll
    for (int k = 0; k < 16; ++k) xv[k] = xr[lane + 64 * k];

    float myl = NEGF;
    for (int e = 0; e < EI; ++e) {
        float s = 0.f;
#pragma unroll
        for (int k = 0; k < 16; ++k) s += xv[k] * gi[(lane + 64 * k) * EI + e];
        for (int off = 32; off; off >>= 1) s += __shfl_xor(s, off);
        if (lane == e) myl = s;
    }

    float v = (lane < EI) ? myl : NEGF;
    float m0 = 0.f, sumexp = 0.f;
    float selv = NEGF; int seli = 0;
    for (int j = 0; j < TOPK; ++j) {
        float bv = v; int bi = lane;
        for (int off = 32; off; off >>= 1) {
            float ov = __shfl_xor(bv, off);
            int   oi = __shfl_xor(bi, off);
            if (ov > bv || (ov == bv && oi < bi)) { bv = ov; bi = oi; }
        }
        if (j == 0) m0 = bv;
        sumexp += expf(bv - m0);
        if (lane == j) { selv = bv; seli = bi; }
        if (lane == bi) v = NEGF;
    }
    if (lane < TOPK) {
        float w = expf(selv - m0) / sumexp;
        int slot = atomicAdd(&counts[seli], 1);
        eidx[seli * T_TOK + slot] = t;
        ew  [seli * T_TOK + slot] = w;
    }

    {
        float p  = (lane < EI) ? expf(myl - m0) : 0.f;
        float ps = p;
        for (int off = 32; off; off >>= 1) ps += __shfl_xor(ps, off);
        if (lane < EI) probs[(long)t * EI + lane] = p / ps;
    }

    float mysl = NEGF;
    for (int e = 0; e < ES; ++e) {
        float s = 0.f;
#pragma unroll
        for (int k = 0; k < 16; ++k) s += xv[k] * gs[(lane + 64 * k) * ES + e];
        for (int off = 32; off; off >>= 1) s += __shfl_xor(s, off);
        if (lane == e) mysl = s;
    }
    {
        float a = (lane < ES) ? mysl : NEGF;
        float mx = a;
        for (int off = 1; off < 4; off <<= 1) mx = fmaxf(mx, __shfl_xor(mx, off));
        float exv = (lane < ES) ? expf(a - mx) : 0.f;
        float se = exv;
        for (int off = 1; off < 4; off <<= 1) se += __shfl_xor(se, off);
        if (lane < ES) {
            int e = EI + lane;
            eidx[(long)e * T_TOK + t] = t;
            ew  [(long)e * T_TOK + t] = exv / se;
        }
    }
}

// =====================================================================
// Prep: x fp32 -> fp16
// =====================================================================
__global__ __launch_bounds__(256) void cvt_x_kernel(
    const float* __restrict__ x, f16* __restrict__ xh)
{
    long i = ((long)blockIdx.x * 256 + threadIdx.x) * 8;
    float4 a = *(const float4*)(x + i);
    float4 b = *(const float4*)(x + i + 4);
    f16x8 o;
    o[0]=(f16)a.x; o[1]=(f16)a.y; o[2]=(f16)a.z; o[3]=(f16)a.w;
    o[4]=(f16)b.x; o[5]=(f16)b.y; o[6]=(f16)b.z; o[7]=(f16)b.w;
    *(f16x8*)(xh + i) = o;
}

// =====================================================================
// Prep: transpose+convert  in[e][R][C] f32 -> out[e][C][R] f16
// =====================================================================
__global__ __launch_bounds__(256) void transpose_cvt_kernel(
    const float* __restrict__ in, f16* __restrict__ out, int R, int C)
{
    __shared__ float tile[64][65];
    const int e = blockIdx.z;
    const long ebase = (long)e * R * C;
    const int r0 = blockIdx.y * 64, c0 = blockIdx.x * 64;
    const int tr = threadIdx.x >> 6, tc = threadIdx.x & 63;
#pragma unroll
    for (int i = 0; i < 16; ++i) {
        int row = i * 4 + tr;
        tile[row][tc] = in[ebase + (long)(r0 + row) * C + c0 + tc];
    }
    __syncthreads();
#pragma unroll
    for (int i = 0; i < 16; ++i) {
        int col = i * 4 + tr;
        out[ebase + (long)(c0 + col) * R + r0 + tc] = (f16)tile[tc][col];
    }
}

// =====================================================================
// Fused fp16-MFMA expert MLP.
// Block: 512 thr / 8 waves, M=64 gathered tokens, out tile 64x1024.
// A (x rows, fp16) staged once in LDS (128 KB, XOR-swizzled).
// Per F-chunk (128): GEMM1 h=relu(A@W1+b1) -> h LDS (16 KB, swizzled),
// GEMM2 acc += h @ W2 into 128 f32 regs/lane. Weighted atomicAdd epilogue.
// Weights streamed fp16 from pre-transposed ws arrays (B-frag = 16B/lane).
// =====================================================================
__global__ __launch_bounds__(512, 2) void expert_fp16_kernel(
    const f16* __restrict__ xh,
    const f16* __restrict__ W1ti, const float* __restrict__ b1i,
    const f16* __restrict__ W2ti, const float* __restrict__ b2i,
    const f16* __restrict__ W1ts, const float* __restrict__ b1s,
    const f16* __restrict__ W2ts, const float* __restrict__ b2s,
    const int* __restrict__ counts,
    const int* __restrict__ eidx, const float* __restrict__ ew,
    float* __restrict__ y)
{
    const int e  = blockIdx.x >> 7;           // 128 M-tiles per expert
    const int bt = blockIdx.x & 127;
    const int n  = (e < EI) ? counts[e] : T_TOK;
    const int base = bt * M_TILE;
    if (base >= n) return;

    const int tid  = threadIdx.x;
    const int wv   = tid >> 6;                // wave 0..7
    const int lane = tid & 63;
    const int lo   = lane & 15;
    const int hi   = lane >> 4;
    const long eT  = (long)e * T_TOK;

    __shared__ f16 As[M_TILE * H_DIM];        // 128 KB, swizzled
    __shared__ f16 Hs[M_TILE * FC];           // 16 KB, swizzled
    __shared__ int toks[M_TILE];

    // ---- select expert weight pointers ----
    const f16 *W1t, *W2t; const float *b1, *b2;
    if (e < EI) {
        W1t = W1ti + (long)e * H_DIM * F_DIM;  b1 = b1i + (long)e * F_DIM;
        W2t = W2ti + (long)e * H_DIM * F_DIM;  b2 = b2i + (long)e * H_DIM;
    } else {
        int s = e - EI;
        W1t = W1ts + (long)s * H_DIM * F_DIM;  b1 = b1s + (long)s * F_DIM;
        W2t = W2ts + (long)s * H_DIM * F_DIM;  b2 = b2s + (long)s * H_DIM;
    }

    if (tid < M_TILE) {
        int gr = base + tid;
        toks[tid] = (gr < n) ? eidx[eT + gr] : eidx[eT];
    }
    __syncthreads();

    // ---- stage A: 64 rows x 2048 B, swizzled byte ^= (row&15)<<4 ----
#pragma unroll
    for (int it = 0; it < 16; ++it) {
        int idx  = it * 512 + tid;            // 8192 16B-slots
        int row  = idx >> 7;
        int slot = idx & 127;
        uint4 v = *(const uint4*)(xh + (long)toks[row] * H_DIM + slot * 8);
        int byte = (row * 2048 + slot * 16) ^ ((row & 15) << 4);
        *(uint4*)((char*)As + byte) = v;
    }
    __syncthreads();

    f32x4 acc2[4][8];
#pragma unroll
    for (int m = 0; m < 4; ++m)
#pragma unroll
        for (int nn = 0; nn < 8; ++nn) acc2[m][nn] = (f32x4){0.f,0.f,0.f,0.f};

    const int col_l = (wv << 4) + lo;         // GEMM1 local col 0..127

    for (int fc = 0; fc < NCHUNK; ++fc) {
        // ================= GEMM1: h[64][16 cols/wave], K=1024 =================
        f32x4 acc1[4];
#pragma unroll
        for (int m = 0; m < 4; ++m) acc1[m] = (f32x4){0.f,0.f,0.f,0.f};

        const f16* w1base = W1t + (long)(fc * FC + col_l) * H_DIM + (hi << 3);
        f16x8 bq[4];
#pragma unroll
        for (int j = 0; j < 4; ++j) bq[j] = *(const f16x8*)(w1base + j * 32);

        for (int ks4 = 0; ks4 < 8; ++ks4) {
#pragma unroll
            for (int j = 0; j < 4; ++j) {
                int ks = ks4 * 4 + j;
#pragma unroll
                for (int m = 0; m < 4; ++m) {
                    int row  = (m << 4) + lo;
                    int byte = (row * 2048 + ks * 64 + (hi << 4)) ^ ((row & 15) << 4);
                    f16x8 af = *(const f16x8*)((const char*)As + byte);
                    acc1[m] = __builtin_amdgcn_mfma_f32_16x16x32_f16(af, bq[j], acc1[m], 0, 0, 0);
                }
                if (ks + 4 < 32) bq[j] = *(const f16x8*)(w1base + (ks + 4) * 32);
            }
        }

        __syncthreads();   // prev chunk's GEMM2 done reading Hs

        // bias + relu + cvt -> Hs (swizzled [64][128])
        float b1v = b1[fc * FC + col_l];
#pragma unroll
        for (int m = 0; m < 4; ++m)
#pragma unroll
            for (int r = 0; r < 4; ++r) {
                int row  = (m << 4) + (hi << 2) + r;
                float hv = fmaxf(acc1[m][r] + b1v, 0.f);
                int byte = (row * 256 + col_l * 2) ^ ((row & 15) << 4);
                *(f16*)((char*)Hs + byte) = (f16)hv;
            }
        __syncthreads();

        // ================= GEMM2: acc2 += h @ W2[fc-chunk, wave cols] =========
#pragma unroll
        for (int ks = 0; ks < 4; ++ks) {
            f16x8 af[4];
#pragma unroll
            for (int m = 0; m < 4; ++m) {
                int row  = (m << 4) + lo;
                int byte = (row * 256 + ks * 64 + (hi << 4)) ^ ((row & 15) << 4);
                af[m] = *(const f16x8*)((const char*)Hs + byte);
            }
            f16x8 bf2a[8];
#pragma unroll
            for (int nn = 0; nn < 8; ++nn) {
                int col = (wv << 7) + (nn << 4) + lo;
                bf2a[nn] = *(const f16x8*)(W2t + (long)col * F_DIM + fc * FC + ks * 32 + (hi << 3));
            }
#pragma unroll
            for (int nn = 0; nn < 8; ++nn)
#pragma unroll
                for (int m = 0; m < 4; ++m)
                    acc2[m][nn] = __builtin_amdgcn_mfma_f32_16x16x32_f16(af[m], bf2a[nn], acc2[m][nn], 0, 0, 0);
        }
    }

    // ---- epilogue: y[tok] += wt * (acc2 + b2) ----
    float b2v[8];
#pragma unroll
    for (int nn = 0; nn < 8; ++nn) b2v[nn] = b2[(wv << 7) + (nn << 4) + lo];

#pragma unroll
    for (int m = 0; m < 4; ++m)
#pragma unroll
        for (int r = 0; r < 4; ++r) {
            int row = (m << 4) + (hi << 2) + r;
            int gr  = base + row;
            if (gr < n) {
                float wt = ew[eT + gr];
                if (wt != 0.f) {
                    int t = toks[row];
                    float* dst = y + (long)t * H_DIM + (wv << 7) + lo;
#pragma unroll
                    for (int nn = 0; nn < 8; ++nn)
                        atomicAdd(dst + (nn << 4), wt * (acc2[m][nn][r] + b2v[nn]));
                }
            }
        }
}

// =====================================================================
// FALLBACK fp32 expert kernel (R1, proven) — used if ws too small
// =====================================================================
#define TT 8
__global__ __launch_bounds__(256) void expert_kernel(
    const float* __restrict__ x,
    const float* __restrict__ W1i, const float* __restrict__ b1i,
    const float* __restrict__ W2i, const float* __restrict__ b2i,
    const float* __restrict__ W1s, const float* __restrict__ b1s,
    const float* __restrict__ W2s, const float* __restrict__ b2s,
    const int*   __restrict__ counts,
    const int*   __restrict__ eidx, const float* __restrict__ ew,
    float* __restrict__ y)
{
    const int e  = blockIdx.x >> 10;
    const int bt = blockIdx.x & 1023;
    const int n  = (e < EI) ? counts[e] : T_TOK;
    const int base = bt * TT;
    if (base >= n) return;
    const int tid = threadIdx.x;

    __shared__ float4 xs4[TT][H_DIM / 4];
    __shared__ float4 hs4[TT][H_DIM / 4];
    __shared__ int   tok[TT];
    __shared__ float twt[TT];

    if (tid < TT) {
        int r = base + tid;
        if (r < n) { tok[tid] = eidx[(long)e * T_TOK + r]; twt[tid] = ew[(long)e * T_TOK + r]; }
        else       { tok[tid] = 0;                          twt[tid] = 0.f; }
    }
    __syncthreads();

#pragma unroll
    for (int i = 0; i < TT; ++i) {
        const float4* src = (const float4*)(x + (long)tok[i] * H_DIM);
        xs4[i][tid] = src[tid];
    }
    __syncthreads();

    const float *W1p, *b1p, *W2p, *b2p;
    if (e < EI) {
        W1p = W1i + (long)e * H_DIM * F_DIM;  b1p = b1i + (long)e * F_DIM;
        W2p = W2i + (long)e * F_DIM * H_DIM;  b2p = b2i + (long)e * H_DIM;
    } else {
        int s = e - EI;
        W1p = W1s + (long)s * H_DIM * F_DIM;  b1p = b1s + (long)s * F_DIM;
        W2p = W2s + (long)s * F_DIM * H_DIM;  b2p = b2s + (long)s * H_DIM;
    }

    float oa[TT][4];
#pragma unroll
    for (int t = 0; t < TT; ++t) { oa[t][0]=0.f; oa[t][1]=0.f; oa[t][2]=0.f; oa[t][3]=0.f; }

    const int c0 = tid * 4;

    for (int half = 0; half < 2; ++half) {
        const int fbase = half * (F_DIM / 2);
        float ba[TT][4];
#pragma unroll
        for (int t = 0; t < TT; ++t) { ba[t][0]=0.f; ba[t][1]=0.f; ba[t][2]=0.f; ba[t][3]=0.f; }

        const float* w1c = W1p + fbase + c0;
        for (int hh4 = 0; hh4 < H_DIM / 4; ++hh4) {
            float4 xv[TT];
#pragma unroll
            for (int t = 0; t < TT; ++t) xv[t] = xs4[t][hh4];
#pragma unroll
            for (int u = 0; u < 4; ++u) {
                float4 w = *(const float4*)(w1c + (long)(hh4 * 4 + u) * F_DIM);
#pragma unroll
                for (int t = 0; t < TT; ++t) {
                    float xu = (u == 0) ? xv[t].x : (u == 1) ? xv[t].y : (u == 2) ? xv[t].z : xv[t].w;
                    ba[t][0] += xu * w.x; ba[t][1] += xu * w.y;
                    ba[t][2] += xu * w.z; ba[t][3] += xu * w.w;
                }
            }
        }

        float4 bb = *(const float4*)(b1p + fbase + c0);
        __syncthreads();
#pragma unroll
        for (int t = 0; t < TT; ++t) {
            float4 hv;
            hv.x = fmaxf(ba[t][0] + bb.x, 0.f);
            hv.y = fmaxf(ba[t][1] + bb.y, 0.f);
            hv.z = fmaxf(ba[t][2] + bb.z, 0.f);
            hv.w = fmaxf(ba[t][3] + bb.w, 0.f);
            hs4[t][tid] = hv;
        }
        __syncthreads();

        const float* w2c = W2p + (long)fbase * H_DIM + c0;
        for (int ff4 = 0; ff4 < H_DIM / 4; ++ff4) {
            float4 hv[TT];
#pragma unroll
            for (int t = 0; t < TT; ++t) hv[t] = hs4[t][ff4];
#pragma unroll
            for (int u = 0; u < 4; ++u) {
                float4 w = *(const float4*)(w2c + (long)(ff4 * 4 + u) * H_DIM);
#pragma unroll
                for (int t = 0; t < TT; ++t) {
                    float hu = (u == 0) ? hv[t].x : (u == 1) ? hv[t].y : (u == 2) ? hv[t].z : hv[t].w;
                    oa[t][0] += hu * w.x; oa[t][1] += hu * w.y;
                    oa[t][2] += hu * w.z; oa[t][3] += hu * w.w;
                }
            }
        }
        __syncthreads();
    }

    float4 b2v = *(const float4*)(b2p + c0);
#pragma unroll
    for (int t = 0; t < TT; ++t) {
        float wt = twt[t];
        if (wt != 0.f) {
            float* dst = y + (long)tok[t] * H_DIM + c0;
            atomicAdd(dst + 0, wt * (oa[t][0] + b2v.x));
            atomicAdd(dst + 1, wt * (oa[t][1] + b2v.y));
            atomicAdd(dst + 2, wt * (oa[t][2] + b2v.z));
            atomicAdd(dst + 3, wt * (oa[t][3] + b2v.w));
        }
    }
}

// =====================================================================
// Aux loss: aux = EI * sum_e (counts[e]/T) * mean_t probs[t][e]
// =====================================================================
__global__ __launch_bounds__(256) void aux_kernel(
    const float* __restrict__ probs, const int* __restrict__ counts,
    float* __restrict__ out)
{
    __shared__ float sacc[256];
    const int per_blk = (T_TOK * EI) / 256;
    long start = (long)blockIdx.x * per_blk;
    float p = 0.f;
    for (int i = threadIdx.x; i < per_blk; i += 256) {
        long idx = start + i;
        p += (float)counts[idx & (EI - 1)] * probs[idx];
    }
    sacc[threadIdx.x] = p;
    __syncthreads();
    for (int s = 128; s; s >>= 1) {
        if (threadIdx.x < s) sacc[threadIdx.x] += sacc[threadIdx.x + s];
        __syncthreads();
    }
    if (threadIdx.x == 0) {
        float scale = (float)EI / ((float)T_TOK * (float)T_TOK);
        atomicAdd(out + (long)T_TOK * H_DIM, scale * sacc[0]);
    }
}

// =====================================================================
extern "C" void kernel_launch(void* const* d_in, const int* in_sizes, int n_in,
                              void* d_out, int out_size, void* d_ws, size_t ws_size,
                              hipStream_t stream)
{
    const float* x    = (const float*)d_in[0];
    const float* gi   = (const float*)d_in[1];
    const float* W1i  = (const float*)d_in[2];
    const float* b1i  = (const float*)d_in[3];
    const float* W2i  = (const float*)d_in[4];
    const float* b2i  = (const float*)d_in[5];
    const float* gs   = (const float*)d_in[6];
    const float* W1s  = (const float*)d_in[7];
    const float* b1s  = (const float*)d_in[8];
    const float* W2s  = (const float*)d_in[9];
    const float* b2s  = (const float*)d_in[10];
    float* y = (float*)d_out;

    char* ws = (char*)d_ws;
    int*   counts = (int*)  (ws);
    int*   eidx   = (int*)  (ws + OFF_EIDX);
    float* ew     = (float*)(ws + OFF_EW);
    float* probs  = (float*)(ws + OFF_PROBS);

    hipMemsetAsync(d_out, 0, (size_t)out_size * sizeof(float), stream);
    hipMemsetAsync(counts, 0, 256, stream);

    gate_kernel<<<T_TOK / 4, 256, 0, stream>>>(x, gi, gs, counts, eidx, ew, probs);
    aux_kernel<<<256, 256, 0, stream>>>(probs, counts, y);

    if (ws_size >= WS_FP16_NEED) {
        // ---------- fp16 MFMA path ----------
        f16* xh   = (f16*)(ws + OFF_XH);
        f16* W1ti = (f16*)(ws + OFF_W1TI);
        f16* W2ti = (f16*)(ws + OFF_W2TI);
        f16* W1ts = (f16*)(ws + OFF_W1TS);
        f16* W2ts = (f16*)(ws + OFF_W2TS);

        cvt_x_kernel<<<(T_TOK * H_DIM) / 8 / 256, 256, 0, stream>>>(x, xh);

        dim3 g1(F_DIM / 64, H_DIM / 64, EI);   // W1i: [E][H][F] -> [E][F][H]
        transpose_cvt_kernel<<<g1, 256, 0, stream>>>(W1i, W1ti, H_DIM, F_DIM);
        dim3 g2(H_DIM / 64, F_DIM / 64, EI);   // W2i: [E][F][H] -> [E][H][F]
        transpose_cvt_kernel<<<g2, 256, 0, stream>>>(W2i, W2ti, F_DIM, H_DIM);
        dim3 g3(F_DIM / 64, H_DIM / 64, ES);
        transpose_cvt_kernel<<<g3, 256, 0, stream>>>(W1s, W1ts, H_DIM, F_DIM);
        dim3 g4(H_DIM / 64, F_DIM / 64, ES);
        transpose_cvt_kernel<<<g4, 256, 0, stream>>>(W2s, W2ts, F_DIM, H_DIM);

        expert_fp16_kernel<<<NE * MT_PER_E, 512, 0, stream>>>(
            xh, W1ti, b1i, W2ti, b2i, W1ts, b1s, W2ts, b2s,
            counts, eidx, ew, y);
    } else {
        // ---------- fallback fp32 path (R1) ----------
        expert_kernel<<<NE * (T_TOK / TT), 256, 0, stream>>>(
            x, W1i, b1i, W2i, b2i, W1s, b1s, W2s, b2s, counts, eidx, ew, y);
    }
}

// Round 5
// 3851.075 us; speedup vs baseline: 7.3055x; 3.0897x over previous
//
#include <hip/hip_runtime.h>
#include <math.h>

// Problem constants (from reference setup_inputs)
#define T_TOK 8192      // B*S = 4*2048 tokens
#define H_DIM 1024
#define F_DIM 2048
#define EI    32        // individual (sparse) experts
#define ES    4         // shared (dense) experts
#define NE    36        // EI + ES
#define TOPK  16

#define NEGF  (-3.0e38f)

typedef _Float16 f16;
typedef _Float16 f16x8 __attribute__((ext_vector_type(8)));
typedef float    f32x4 __attribute__((ext_vector_type(4)));
typedef unsigned int u32;

// ---------------- workspace layout (bytes) ----------------
#define OFF_EIDX   256
#define OFF_EW     (OFF_EIDX + NE*T_TOK*4)
#define OFF_PROBS  (OFF_EW   + NE*T_TOK*4)
#define OFF_XH     (OFF_PROBS + T_TOK*EI*4)
#define OFF_W1TI   (OFF_XH   + T_TOK*H_DIM*2)
#define OFF_W2TI   (OFF_W1TI + (size_t)EI*H_DIM*F_DIM*2)
#define OFF_W1TS   (OFF_W2TI + (size_t)EI*H_DIM*F_DIM*2)
#define OFF_W2TS   (OFF_W1TS + (size_t)ES*H_DIM*F_DIM*2)
#define WS_FP16_NEED (OFF_W2TS + (size_t)ES*H_DIM*F_DIM*2)
// two-pass h buffer (chunked by expert): one slab = 8192x2048 f16 = 33.55MB
#define OFF_H      ((WS_FP16_NEED + 4095) & ~(size_t)4095)
#define H_SLAB     ((size_t)T_TOK * F_DIM * 2)

// fused-path tile config (fallback)
#define M_TILE 64
#define FC     128
#define NCHUNK (F_DIM/FC)
#define MT_PER_E (T_TOK/M_TILE)

// grouped-GEMM tile config
#define TM  128
#define TN  128
#define BK  64
#define BKB (BK*2)   // 128 bytes of f16 per row per K-step

// direct global->LDS 16B async copy
__device__ __forceinline__ void gload_lds16(const void* g, void* l) {
    __builtin_amdgcn_global_load_lds(
        (const __attribute__((address_space(1))) u32*)g,
        (__attribute__((address_space(3))) u32*)l, 16, 0, 0);
}

// =====================================================================
// Gate: logits, softmax, top-16, gather lists, shared-expert weights
// =====================================================================
__global__ __launch_bounds__(256) void gate_kernel(
    const float* __restrict__ x,
    const float* __restrict__ gi,   // [H][EI]
    const float* __restrict__ gs,   // [H][ES]
    int*   __restrict__ counts,
    int*   __restrict__ eidx,
    float* __restrict__ ew,
    float* __restrict__ probs)
{
    const int wave = threadIdx.x >> 6;
    const int lane = threadIdx.x & 63;
    const int t = blockIdx.x * 4 + wave;

    const float* xr = x + (long)t * H_DIM;
    float xv[16];
#pragma unroll
    for (int k = 0; k < 16; ++k) xv[k] = xr[lane + 64 * k];

    float myl = NEGF;
    for (int e = 0; e < EI; ++e) {
        float s = 0.f;
#pragma unroll
        for (int k = 0; k < 16; ++k) s += xv[k] * gi[(lane + 64 * k) * EI + e];
        for (int off = 32; off; off >>= 1) s += __shfl_xor(s, off);
        if (lane == e) myl = s;
    }

    float v = (lane < EI) ? myl : NEGF;
    float m0 = 0.f, sumexp = 0.f;
    float selv = NEGF; int seli = 0;
    for (int j = 0; j < TOPK; ++j) {
        float bv = v; int bi = lane;
        for (int off = 32; off; off >>= 1) {
            float ov = __shfl_xor(bv, off);
            int   oi = __shfl_xor(bi, off);
            if (ov > bv || (ov == bv && oi < bi)) { bv = ov; bi = oi; }
        }
        if (j == 0) m0 = bv;
        sumexp += expf(bv - m0);
        if (lane == j) { selv = bv; seli = bi; }
        if (lane == bi) v = NEGF;
    }
    if (lane < TOPK) {
        float w = expf(selv - m0) / sumexp;
        int slot = atomicAdd(&counts[seli], 1);
        eidx[seli * T_TOK + slot] = t;
        ew  [seli * T_TOK + slot] = w;
    }

    {
        float p  = (lane < EI) ? expf(myl - m0) : 0.f;
        float ps = p;
        for (int off = 32; off; off >>= 1) ps += __shfl_xor(ps, off);
        if (lane < EI) probs[(long)t * EI + lane] = p / ps;
    }

    float mysl = NEGF;
    for (int e = 0; e < ES; ++e) {
        float s = 0.f;
#pragma unroll
        for (int k = 0; k < 16; ++k) s += xv[k] * gs[(lane + 64 * k) * ES + e];
        for (int off = 32; off; off >>= 1) s += __shfl_xor(s, off);
        if (lane == e) mysl = s;
    }
    {
        float a = (lane < ES) ? mysl : NEGF;
        float mx = a;
        for (int off = 1; off < 4; off <<= 1) mx = fmaxf(mx, __shfl_xor(mx, off));
        float exv = (lane < ES) ? expf(a - mx) : 0.f;
        float se = exv;
        for (int off = 1; off < 4; off <<= 1) se += __shfl_xor(se, off);
        if (lane < ES) {
            int e = EI + lane;
            eidx[(long)e * T_TOK + t] = t;
            ew  [(long)e * T_TOK + t] = exv / se;
        }
    }
}

// =====================================================================
// Prep: x fp32 -> fp16
// =====================================================================
__global__ __launch_bounds__(256) void cvt_x_kernel(
    const float* __restrict__ x, f16* __restrict__ xh)
{
    long i = ((long)blockIdx.x * 256 + threadIdx.x) * 8;
    float4 a = *(const float4*)(x + i);
    float4 b = *(const float4*)(x + i + 4);
    f16x8 o;
    o[0]=(f16)a.x; o[1]=(f16)a.y; o[2]=(f16)a.z; o[3]=(f16)a.w;
    o[4]=(f16)b.x; o[5]=(f16)b.y; o[6]=(f16)b.z; o[7]=(f16)b.w;
    *(f16x8*)(xh + i) = o;
}

// =====================================================================
// Prep: transpose+convert  in[e][R][C] f32 -> out[e][C][R] f16
// =====================================================================
__global__ __launch_bounds__(256) void transpose_cvt_kernel(
    const float* __restrict__ in, f16* __restrict__ out, int R, int C)
{
    __shared__ float tile[64][65];
    const int e = blockIdx.z;
    const long ebase = (long)e * R * C;
    const int r0 = blockIdx.y * 64, c0 = blockIdx.x * 64;
    const int tr = threadIdx.x >> 6, tc = threadIdx.x & 63;
#pragma unroll
    for (int i = 0; i < 16; ++i) {
        int row = i * 4 + tr;
        tile[row][tc] = in[ebase + (long)(r0 + row) * C + c0 + tc];
    }
    __syncthreads();
#pragma unroll
    for (int i = 0; i < 16; ++i) {
        int col = i * 4 + tr;
        out[ebase + (long)(c0 + col) * R + r0 + tc] = (f16)tile[tc][col];
    }
}

// =====================================================================
// Pass A: grouped GEMM1  h[e][slot][f] = relu(x[tok] @ W1^T + b1)
// m97 structure: 128x128 tile, BK=64, global_load_lds dbuf, 1 barrier/step.
// A rows gathered (token ids); source slots pre-XOR-swizzled so the
// linear-dest LDS reads back conflict-free (2-way max) as ds_read_b128.
// =====================================================================
__global__ __launch_bounds__(256, 2) void gemm1_kernel(
    const f16* __restrict__ xh,
    const f16* __restrict__ W1ti, const float* __restrict__ b1i,
    const f16* __restrict__ W1ts, const float* __restrict__ b1s,
    const int* __restrict__ counts, const int* __restrict__ eidx,
    f16* __restrict__ h, int e0)
{
    const int e = e0 + blockIdx.z;
    const int n = (e < EI) ? counts[e] : T_TOK;
    const int base = blockIdx.y * TM;
    if (base >= n) return;
    const int n0 = blockIdx.x * TN;

    const int tid = threadIdx.x;
    const int wv = tid >> 6, lane = tid & 63, lo = lane & 15, hi = lane >> 4;
    const int wr = wv >> 1, wc = wv & 1;
    const long eT = (long)e * T_TOK;

    __shared__ f16 As[2][TM * BK];
    __shared__ f16 Bs[2][TN * BK];
    __shared__ int tokLds[TM];

    const f16* W1t; const float* b1;
    if (e < EI) { W1t = W1ti + (long)e * H_DIM * F_DIM;      b1 = b1i + (long)e * F_DIM; }
    else        { W1t = W1ts + (long)(e-EI) * H_DIM * F_DIM; b1 = b1s + (long)(e-EI) * F_DIM; }

    if (tid < TM) {
        int gr = base + tid;
        tokLds[tid] = (gr < n) ? eidx[eT + gr] : eidx[eT];
    }
    __syncthreads();

    // per-thread staging descriptors: 4 A-slots + 4 B-slots of 16B
    const char* asrc[4]; const char* bsrc[4]; int dst[4];
#pragma unroll
    for (int i = 0; i < 4; ++i) {
        int slot = i * 256 + tid;          // 0..1023
        int row = slot >> 3, si = slot & 7;
        dst[i]  = slot * 16;
        asrc[i] = (const char*)xh + (long)tokLds[row] * 2048 + ((si ^ (row & 7)) << 4);
        bsrc[i] = (const char*)W1t + (long)(n0 + row) * 2048 + ((si ^ (row & 7)) << 4);
    }

    f32x4 acc[4][4];
#pragma unroll
    for (int m = 0; m < 4; ++m)
#pragma unroll
        for (int nf = 0; nf < 4; ++nf) acc[m][nf] = (f32x4){0.f,0.f,0.f,0.f};

#define STAGE1(buf, kt) do { long ko = (long)(kt) * BKB;                      \
    _Pragma("unroll") for (int i = 0; i < 4; ++i)                             \
        gload_lds16(asrc[i] + ko, (char*)As[buf] + dst[i]);                   \
    _Pragma("unroll") for (int i = 0; i < 4; ++i)                             \
        gload_lds16(bsrc[i] + ko, (char*)Bs[buf] + dst[i]); } while (0)

    STAGE1(0, 0);
    __syncthreads();
    int buf = 0;
    const int NT1 = H_DIM / BK;            // 16
    for (int kt = 0; kt < NT1; ++kt) {
        if (kt + 1 < NT1) STAGE1(buf ^ 1, kt + 1);
#pragma unroll
        for (int ks = 0; ks < 2; ++ks) {
            f16x8 a[4], b[4];
#pragma unroll
            for (int m = 0; m < 4; ++m) {
                int row = wr * 64 + m * 16 + lo;
                int byte = row * BKB + ((((ks << 2) + hi) ^ (row & 7)) << 4);
                a[m] = *(const f16x8*)((const char*)As[buf] + byte);
            }
#pragma unroll
            for (int nf = 0; nf < 4; ++nf) {
                int col = wc * 64 + nf * 16 + lo;
                int byte = col * BKB + ((((ks << 2) + hi) ^ (col & 7)) << 4);
                b[nf] = *(const f16x8*)((const char*)Bs[buf] + byte);
            }
#pragma unroll
            for (int nf = 0; nf < 4; ++nf)
#pragma unroll
                for (int m = 0; m < 4; ++m)
                    acc[m][nf] = __builtin_amdgcn_mfma_f32_16x16x32_f16(a[m], b[nf], acc[m][nf], 0, 0, 0);
        }
        __syncthreads();
        buf ^= 1;
    }

    // epilogue: bias + relu + fp16 -> h[ez][base+row][n0+col]
    f16* hz = h + (long)blockIdx.z * T_TOK * F_DIM;
    float b1v[4];
#pragma unroll
    for (int nf = 0; nf < 4; ++nf) b1v[nf] = b1[n0 + wc * 64 + nf * 16 + lo];
#pragma unroll
    for (int m = 0; m < 4; ++m)
#pragma unroll
        for (int r = 0; r < 4; ++r) {
            int grow = base + wr * 64 + m * 16 + hi * 4 + r;
            if (grow < n) {
                f16* hp = hz + (long)grow * F_DIM + n0 + wc * 64 + lo;
#pragma unroll
                for (int nf = 0; nf < 4; ++nf)
                    hp[nf * 16] = (f16)fmaxf(acc[m][nf][r] + b1v[nf], 0.f);
            }
        }
}

// =====================================================================
// Pass B: grouped GEMM2  y[tok] += ew * (h @ W2^T + b2)   (atomicAdd)
// =====================================================================
__global__ __launch_bounds__(256, 2) void gemm2_kernel(
    const f16* __restrict__ h,
    const f16* __restrict__ W2ti, const float* __restrict__ b2i,
    const f16* __restrict__ W2ts, const float* __restrict__ b2s,
    const int* __restrict__ counts, const int* __restrict__ eidx,
    const float* __restrict__ ew,
    float* __restrict__ y, int e0)
{
    const int e = e0 + blockIdx.z;
    const int n = (e < EI) ? counts[e] : T_TOK;
    const int base = blockIdx.y * TM;
    if (base >= n) return;
    const int n0 = blockIdx.x * TN;       // output col tile (H_DIM/128 = 8)

    const int tid = threadIdx.x;
    const int wv = tid >> 6, lane = tid & 63, lo = lane & 15, hi = lane >> 4;
    const int wr = wv >> 1, wc = wv & 1;
    const long eT = (long)e * T_TOK;

    __shared__ f16 As[2][TM * BK];
    __shared__ f16 Bs[2][TN * BK];

    const f16* W2t; const float* b2;
    if (e < EI) { W2t = W2ti + (long)e * H_DIM * F_DIM;      b2 = b2i + (long)e * H_DIM; }
    else        { W2t = W2ts + (long)(e-EI) * H_DIM * F_DIM; b2 = b2s + (long)(e-EI) * H_DIM; }

    const f16* hz = h + (long)blockIdx.z * T_TOK * F_DIM;

    const char* asrc[4]; const char* bsrc[4]; int dst[4];
#pragma unroll
    for (int i = 0; i < 4; ++i) {
        int slot = i * 256 + tid;
        int row = slot >> 3, si = slot & 7;
        dst[i]  = slot * 16;
        asrc[i] = (const char*)hz + (long)(base + row) * (F_DIM * 2) + ((si ^ (row & 7)) << 4);
        bsrc[i] = (const char*)W2t + (long)(n0 + row) * (F_DIM * 2) + ((si ^ (row & 7)) << 4);
    }

    f32x4 acc[4][4];
#pragma unroll
    for (int m = 0; m < 4; ++m)
#pragma unroll
        for (int nf = 0; nf < 4; ++nf) acc[m][nf] = (f32x4){0.f,0.f,0.f,0.f};

    STAGE1(0, 0);
    __syncthreads();
    int buf = 0;
    const int NT2 = F_DIM / BK;            // 32
    for (int kt = 0; kt < NT2; ++kt) {
        if (kt + 1 < NT2) STAGE1(buf ^ 1, kt + 1);
#pragma unroll
        for (int ks = 0; ks < 2; ++ks) {
            f16x8 a[4], b[4];
#pragma unroll
            for (int m = 0; m < 4; ++m) {
                int row = wr * 64 + m * 16 + lo;
                int byte = row * BKB + ((((ks << 2) + hi) ^ (row & 7)) << 4);
                a[m] = *(const f16x8*)((const char*)As[buf] + byte);
            }
#pragma unroll
            for (int nf = 0; nf < 4; ++nf) {
                int col = wc * 64 + nf * 16 + lo;
                int byte = col * BKB + ((((ks << 2) + hi) ^ (col & 7)) << 4);
                b[nf] = *(const f16x8*)((const char*)Bs[buf] + byte);
            }
#pragma unroll
            for (int nf = 0; nf < 4; ++nf)
#pragma unroll
                for (int m = 0; m < 4; ++m)
                    acc[m][nf] = __builtin_amdgcn_mfma_f32_16x16x32_f16(a[m], b[nf], acc[m][nf], 0, 0, 0);
        }
        __syncthreads();
        buf ^= 1;
    }

    float b2v[4];
#pragma unroll
    for (int nf = 0; nf < 4; ++nf) b2v[nf] = b2[n0 + wc * 64 + nf * 16 + lo];
#pragma unroll
    for (int m = 0; m < 4; ++m)
#pragma unroll
        for (int r = 0; r < 4; ++r) {
            int grow = base + wr * 64 + m * 16 + hi * 4 + r;
            if (grow < n) {
                float wt = ew[eT + grow];
                if (wt != 0.f) {
                    int tok = eidx[eT + grow];
                    float* dstp = y + (long)tok * H_DIM + n0 + wc * 64 + lo;
#pragma unroll
                    for (int nf = 0; nf < 4; ++nf)
                        atomicAdd(dstp + nf * 16, wt * (acc[m][nf][r] + b2v[nf]));
                }
            }
        }
}

// =====================================================================
// FALLBACK 1: fused fp16-MFMA expert MLP (R4, proven 11.9ms)
// =====================================================================
__global__ __launch_bounds__(512, 2) void expert_fp16_kernel(
    const f16* __restrict__ xh,
    const f16* __restrict__ W1ti, const float* __restrict__ b1i,
    const f16* __restrict__ W2ti, const float* __restrict__ b2i,
    const f16* __restrict__ W1ts, const float* __restrict__ b1s,
    const f16* __restrict__ W2ts, const float* __restrict__ b2s,
    const int* __restrict__ counts,
    const int* __restrict__ eidx, const float* __restrict__ ew,
    float* __restrict__ y)
{
    const int e  = blockIdx.x >> 7;
    const int bt = blockIdx.x & 127;
    const int n  = (e < EI) ? counts[e] : T_TOK;
    const int base = bt * M_TILE;
    if (base >= n) return;

    const int tid  = threadIdx.x;
    const int wv   = tid >> 6;
    const int lane = tid & 63;
    const int lo   = lane & 15;
    const int hi   = lane >> 4;
    const long eT  = (long)e * T_TOK;

    __shared__ f16 Asf[M_TILE * H_DIM];
    __shared__ f16 Hs[M_TILE * FC];
    __shared__ int toks[M_TILE];

    const f16 *W1t, *W2t; const float *b1, *b2;
    if (e < EI) {
        W1t = W1ti + (long)e * H_DIM * F_DIM;  b1 = b1i + (long)e * F_DIM;
        W2t = W2ti + (long)e * H_DIM * F_DIM;  b2 = b2i + (long)e * H_DIM;
    } else {
        int s = e - EI;
        W1t = W1ts + (long)s * H_DIM * F_DIM;  b1 = b1s + (long)s * F_DIM;
        W2t = W2ts + (long)s * H_DIM * F_DIM;  b2 = b2s + (long)s * H_DIM;
    }

    if (tid < M_TILE) {
        int gr = base + tid;
        toks[tid] = (gr < n) ? eidx[eT + gr] : eidx[eT];
    }
    __syncthreads();

#pragma unroll
    for (int it = 0; it < 16; ++it) {
        int idx  = it * 512 + tid;
        int row  = idx >> 7;
        int slot = idx & 127;
        uint4 v = *(const uint4*)(xh + (long)toks[row] * H_DIM + slot * 8);
        int byte = (row * 2048 + slot * 16) ^ ((row & 15) << 4);
        *(uint4*)((char*)Asf + byte) = v;
    }
    __syncthreads();

    f32x4 acc2[4][8];
#pragma unroll
    for (int m = 0; m < 4; ++m)
#pragma unroll
        for (int nn = 0; nn < 8; ++nn) acc2[m][nn] = (f32x4){0.f,0.f,0.f,0.f};

    const int col_l = (wv << 4) + lo;

    for (int fc = 0; fc < NCHUNK; ++fc) {
        f32x4 acc1[4];
#pragma unroll
        for (int m = 0; m < 4; ++m) acc1[m] = (f32x4){0.f,0.f,0.f,0.f};

        const f16* w1base = W1t + (long)(fc * FC + col_l) * H_DIM + (hi << 3);
        f16x8 bq[4];
#pragma unroll
        for (int j = 0; j < 4; ++j) bq[j] = *(const f16x8*)(w1base + j * 32);

        for (int ks4 = 0; ks4 < 8; ++ks4) {
#pragma unroll
            for (int j = 0; j < 4; ++j) {
                int ks = ks4 * 4 + j;
#pragma unroll
                for (int m = 0; m < 4; ++m) {
                    int row  = (m << 4) + lo;
                    int byte = (row * 2048 + ks * 64 + (hi << 4)) ^ ((row & 15) << 4);
                    f16x8 af = *(const f16x8*)((const char*)Asf + byte);
                    acc1[m] = __builtin_amdgcn_mfma_f32_16x16x32_f16(af, bq[j], acc1[m], 0, 0, 0);
                }
                if (ks + 4 < 32) bq[j] = *(const f16x8*)(w1base + (ks + 4) * 32);
            }
        }

        __syncthreads();
        float b1v = b1[fc * FC + col_l];
#pragma unroll
        for (int m = 0; m < 4; ++m)
#pragma unroll
            for (int r = 0; r < 4; ++r) {
                int row  = (m << 4) + (hi << 2) + r;
                float hv = fmaxf(acc1[m][r] + b1v, 0.f);
                int byte = (row * 256 + col_l * 2) ^ ((row & 15) << 4);
                *(f16*)((char*)Hs + byte) = (f16)hv;
            }
        __syncthreads();

#pragma unroll
        for (int ks = 0; ks < 4; ++ks) {
            f16x8 af[4];
#pragma unroll
            for (int m = 0; m < 4; ++m) {
                int row  = (m << 4) + lo;
                int byte = (row * 256 + ks * 64 + (hi << 4)) ^ ((row & 15) << 4);
                af[m] = *(const f16x8*)((const char*)Hs + byte);
            }
            f16x8 bf2a[8];
#pragma unroll
            for (int nn = 0; nn < 8; ++nn) {
                int col = (wv << 7) + (nn << 4) + lo;
                bf2a[nn] = *(const f16x8*)(W2t + (long)col * F_DIM + fc * FC + ks * 32 + (hi << 3));
            }
#pragma unroll
            for (int nn = 0; nn < 8; ++nn)
#pragma unroll
                for (int m = 0; m < 4; ++m)
                    acc2[m][nn] = __builtin_amdgcn_mfma_f32_16x16x32_f16(af[m], bf2a[nn], acc2[m][nn], 0, 0, 0);
        }
    }

    float b2v[8];
#pragma unroll
    for (int nn = 0; nn < 8; ++nn) b2v[nn] = b2[(wv << 7) + (nn << 4) + lo];

#pragma unroll
    for (int m = 0; m < 4; ++m)
#pragma unroll
        for (int r = 0; r < 4; ++r) {
            int row = (m << 4) + (hi << 2) + r;
            int gr  = base + row;
            if (gr < n) {
                float wt = ew[eT + gr];
                if (wt != 0.f) {
                    int t = toks[row];
                    float* dstp = y + (long)t * H_DIM + (wv << 7) + lo;
#pragma unroll
                    for (int nn = 0; nn < 8; ++nn)
                        atomicAdd(dstp + (nn << 4), wt * (acc2[m][nn][r] + b2v[nn]));
                }
            }
        }
}

// =====================================================================
// FALLBACK 2: fp32 expert kernel (R1, proven)
// =====================================================================
#define TT 8
__global__ __launch_bounds__(256) void expert_kernel(
    const float* __restrict__ x,
    const float* __restrict__ W1i, const float* __restrict__ b1i,
    const float* __restrict__ W2i, const float* __restrict__ b2i,
    const float* __restrict__ W1s, const float* __restrict__ b1s,
    const float* __restrict__ W2s, const float* __restrict__ b2s,
    const int*   __restrict__ counts,
    const int*   __restrict__ eidx, const float* __restrict__ ew,
    float* __restrict__ y)
{
    const int e  = blockIdx.x >> 10;
    const int bt = blockIdx.x & 1023;
    const int n  = (e < EI) ? counts[e] : T_TOK;
    const int base = bt * TT;
    if (base >= n) return;
    const int tid = threadIdx.x;

    __shared__ float4 xs4[TT][H_DIM / 4];
    __shared__ float4 hs4[TT][H_DIM / 4];
    __shared__ int   tok[TT];
    __shared__ float twt[TT];

    if (tid < TT) {
        int r = base + tid;
        if (r < n) { tok[tid] = eidx[(long)e * T_TOK + r]; twt[tid] = ew[(long)e * T_TOK + r]; }
        else       { tok[tid] = 0;                          twt[tid] = 0.f; }
    }
    __syncthreads();

#pragma unroll
    for (int i = 0; i < TT; ++i) {
        const float4* src = (const float4*)(x + (long)tok[i] * H_DIM);
        xs4[i][tid] = src[tid];
    }
    __syncthreads();

    const float *W1p, *b1p, *W2p, *b2p;
    if (e < EI) {
        W1p = W1i + (long)e * H_DIM * F_DIM;  b1p = b1i + (long)e * F_DIM;
        W2p = W2i + (long)e * F_DIM * H_DIM;  b2p = b2i + (long)e * H_DIM;
    } else {
        int s = e - EI;
        W1p = W1s + (long)s * H_DIM * F_DIM;  b1p = b1s + (long)s * F_DIM;
        W2p = W2s + (long)s * F_DIM * H_DIM;  b2p = b2s + (long)s * H_DIM;
    }

    float oa[TT][4];
#pragma unroll
    for (int t = 0; t < TT; ++t) { oa[t][0]=0.f; oa[t][1]=0.f; oa[t][2]=0.f; oa[t][3]=0.f; }

    const int c0 = tid * 4;

    for (int half = 0; half < 2; ++half) {
        const int fbase = half * (F_DIM / 2);
        float ba[TT][4];
#pragma unroll
        for (int t = 0; t < TT; ++t) { ba[t][0]=0.f; ba[t][1]=0.f; ba[t][2]=0.f; ba[t][3]=0.f; }

        const float* w1c = W1p + fbase + c0;
        for (int hh4 = 0; hh4 < H_DIM / 4; ++hh4) {
            float4 xv[TT];
#pragma unroll
            for (int t = 0; t < TT; ++t) xv[t] = xs4[t][hh4];
#pragma unroll
            for (int u = 0; u < 4; ++u) {
                float4 w = *(const float4*)(w1c + (long)(hh4 * 4 + u) * F_DIM);
#pragma unroll
                for (int t = 0; t < TT; ++t) {
                    float xu = (u == 0) ? xv[t].x : (u == 1) ? xv[t].y : (u == 2) ? xv[t].z : xv[t].w;
                    ba[t][0] += xu * w.x; ba[t][1] += xu * w.y;
                    ba[t][2] += xu * w.z; ba[t][3] += xu * w.w;
                }
            }
        }

        float4 bb = *(const float4*)(b1p + fbase + c0);
        __syncthreads();
#pragma unroll
        for (int t = 0; t < TT; ++t) {
            float4 hv;
            hv.x = fmaxf(ba[t][0] + bb.x, 0.f);
            hv.y = fmaxf(ba[t][1] + bb.y, 0.f);
            hv.z = fmaxf(ba[t][2] + bb.z, 0.f);
            hv.w = fmaxf(ba[t][3] + bb.w, 0.f);
            hs4[t][tid] = hv;
        }
        __syncthreads();

        const float* w2c = W2p + (long)fbase * H_DIM + c0;
        for (int ff4 = 0; ff4 < H_DIM / 4; ++ff4) {
            float4 hv[TT];
#pragma unroll
            for (int t = 0; t < TT; ++t) hv[t] = hs4[t][ff4];
#pragma unroll
            for (int u = 0; u < 4; ++u) {
                float4 w = *(const float4*)(w2c + (long)(ff4 * 4 + u) * H_DIM);
#pragma unroll
                for (int t = 0; t < TT; ++t) {
                    float hu = (u == 0) ? hv[t].x : (u == 1) ? hv[t].y : (u == 2) ? hv[t].z : hv[t].w;
                    oa[t][0] += hu * w.x; oa[t][1] += hu * w.y;
                    oa[t][2] += hu * w.z; oa[t][3] += hu * w.w;
                }
            }
        }
        __syncthreads();
    }

    float4 b2v = *(const float4*)(b2p + c0);
#pragma unroll
    for (int t = 0; t < TT; ++t) {
        float wt = twt[t];
        if (wt != 0.f) {
            float* dstp = y + (long)tok[t] * H_DIM + c0;
            atomicAdd(dstp + 0, wt * (oa[t][0] + b2v.x));
            atomicAdd(dstp + 1, wt * (oa[t][1] + b2v.y));
            atomicAdd(dstp + 2, wt * (oa[t][2] + b2v.z));
            atomicAdd(dstp + 3, wt * (oa[t][3] + b2v.w));
        }
    }
}

// =====================================================================
// Aux loss
// =====================================================================
__global__ __launch_bounds__(256) void aux_kernel(
    const float* __restrict__ probs, const int* __restrict__ counts,
    float* __restrict__ out)
{
    __shared__ float sacc[256];
    const int per_blk = (T_TOK * EI) / 256;
    long start = (long)blockIdx.x * per_blk;
    float p = 0.f;
    for (int i = threadIdx.x; i < per_blk; i += 256) {
        long idx = start + i;
        p += (float)counts[idx & (EI - 1)] * probs[idx];
    }
    sacc[threadIdx.x] = p;
    __syncthreads();
    for (int s = 128; s; s >>= 1) {
        if (threadIdx.x < s) sacc[threadIdx.x] += sacc[threadIdx.x + s];
        __syncthreads();
    }
    if (threadIdx.x == 0) {
        float scale = (float)EI / ((float)T_TOK * (float)T_TOK);
        atomicAdd(out + (long)T_TOK * H_DIM, scale * sacc[0]);
    }
}

// =====================================================================
extern "C" void kernel_launch(void* const* d_in, const int* in_sizes, int n_in,
                              void* d_out, int out_size, void* d_ws, size_t ws_size,
                              hipStream_t stream)
{
    const float* x    = (const float*)d_in[0];
    const float* gi   = (const float*)d_in[1];
    const float* W1i  = (const float*)d_in[2];
    const float* b1i  = (const float*)d_in[3];
    const float* W2i  = (const float*)d_in[4];
    const float* b2i  = (const float*)d_in[5];
    const float* gs   = (const float*)d_in[6];
    const float* W1s  = (const float*)d_in[7];
    const float* b1s  = (const float*)d_in[8];
    const float* W2s  = (const float*)d_in[9];
    const float* b2s  = (const float*)d_in[10];
    float* y = (float*)d_out;

    char* ws = (char*)d_ws;
    int*   counts = (int*)  (ws);
    int*   eidx   = (int*)  (ws + OFF_EIDX);
    float* ew     = (float*)(ws + OFF_EW);
    float* probs  = (float*)(ws + OFF_PROBS);

    hipMemsetAsync(d_out, 0, (size_t)out_size * sizeof(float), stream);
    hipMemsetAsync(counts, 0, 256, stream);

    gate_kernel<<<T_TOK / 4, 256, 0, stream>>>(x, gi, gs, counts, eidx, ew, probs);
    aux_kernel<<<256, 256, 0, stream>>>(probs, counts, y);

    if (ws_size < WS_FP16_NEED) {
        // ---------- fp32 fallback ----------
        expert_kernel<<<NE * (T_TOK / TT), 256, 0, stream>>>(
            x, W1i, b1i, W2i, b2i, W1s, b1s, W2s, b2s, counts, eidx, ew, y);
        return;
    }

    // ---------- fp16 prep (shared by both fp16 paths) ----------
    f16* xh   = (f16*)(ws + OFF_XH);
    f16* W1ti = (f16*)(ws + OFF_W1TI);
    f16* W2ti = (f16*)(ws + OFF_W2TI);
    f16* W1ts = (f16*)(ws + OFF_W1TS);
    f16* W2ts = (f16*)(ws + OFF_W2TS);

    cvt_x_kernel<<<(T_TOK * H_DIM) / 8 / 256, 256, 0, stream>>>(x, xh);

    dim3 g1(F_DIM / 64, H_DIM / 64, EI);
    transpose_cvt_kernel<<<g1, 256, 0, stream>>>(W1i, W1ti, H_DIM, F_DIM);
    dim3 g2(H_DIM / 64, F_DIM / 64, EI);
    transpose_cvt_kernel<<<g2, 256, 0, stream>>>(W2i, W2ti, F_DIM, H_DIM);
    dim3 g3(F_DIM / 64, H_DIM / 64, ES);
    transpose_cvt_kernel<<<g3, 256, 0, stream>>>(W1s, W1ts, H_DIM, F_DIM);
    dim3 g4(H_DIM / 64, F_DIM / 64, ES);
    transpose_cvt_kernel<<<g4, 256, 0, stream>>>(W2s, W2ts, F_DIM, H_DIM);

    // expert-chunk capacity for the two-pass h buffer
    int CS = 0;
    if (ws_size > OFF_H) CS = (int)((ws_size - OFF_H) / H_SLAB);
    if (CS > NE) CS = NE;

    if (CS >= 1) {
        // ---------- two-pass grouped GEMM (fast path) ----------
        f16* hbuf = (f16*)(ws + OFF_H);
        for (int c0 = 0; c0 < NE; c0 += CS) {
            int ce = (NE - c0 < CS) ? (NE - c0) : CS;
            dim3 ga(F_DIM / TN, T_TOK / TM, ce);   // 16 x 64 x ce
            gemm1_kernel<<<ga, 256, 0, stream>>>(
                xh, W1ti, b1i, W1ts, b1s, counts, eidx, hbuf, c0);
            dim3 gb(H_DIM / TN, T_TOK / TM, ce);   // 8 x 64 x ce
            gemm2_kernel<<<gb, 256, 0, stream>>>(
                hbuf, W2ti, b2i, W2ts, b2s, counts, eidx, ew, y, c0);
        }
    } else {
        // ---------- fused fp16 fallback (R4 proven) ----------
        expert_fp16_kernel<<<NE * MT_PER_E, 512, 0, stream>>>(
            xh, W1ti, b1i, W2ti, b2i, W1ts, b1s, W2ts, b2s,
            counts, eidx, ew, y);
    }
}